// Round 9
// baseline (461.298 us; speedup 1.0000x reference)
//
#include <hip/hip_runtime.h>
#include <cstdint>
#include <cstddef>

#define NB 32
#define NN 1024
#define ND 256
#define KNNK 16

// ---------------------------------------------------------------------------
// Kernel A v3: fused positional-add + dual projection GEMM, TRANSPOSED out:
//   Qt [B, 256, 1024], Kt [B, 256, 1024]   (out[e][n] = sum_d h[n][d] w[e][d])
// Tile: 64 e x 64 n, 256 threads, 4x4 microtile. (measured ~90 us)
// ---------------------------------------------------------------------------
__global__ __launch_bounds__(256) void proj_kernel(
    const float* __restrict__ x, const float* __restrict__ pos,
    const float* __restrict__ wq, const float* __restrict__ bq,
    const float* __restrict__ wk, const float* __restrict__ bk,
    float* __restrict__ Qt, float* __restrict__ Kt)
{
    __shared__ __align__(16) float Hs[16][64];   // [d][n_local]
    __shared__ __align__(16) float Ws[16][64];   // [d][e_local]

    const int tid = threadIdx.x;
    const int tx = tid & 15;          // n microtile index
    const int ty = tid >> 4;          // e microtile index
    const int bm = blockIdx.x >> 3;   // 0..511 n tiles (b*16 + ntile)
    const int be = blockIdx.x & 7;    // 0..7 e tiles (0-3 -> Q, 4-7 -> K)
    const int nBase = bm << 6;        // global flattened n base (b*1024 + n0)
    const int b  = nBase >> 10;
    const int n0 = nBase & 1023;
    const int eBase = be << 6;
    const bool isQ = (eBase < 256);
    const float* __restrict__ W    = isQ ? wq : wk;
    const float* __restrict__ bias = isQ ? bq : bk;
    float* __restrict__ Og         = isQ ? Qt : Kt;
    const int e0 = isQ ? eBase : (eBase - 256);

    const int sr = tid >> 2;          // 0..63 (n or e index for staging)
    const int sd = (tid & 3) << 2;    // 0,4,8,12

    float acc[4][4];
    #pragma unroll
    for (int i = 0; i < 4; ++i)
        #pragma unroll
        for (int j = 0; j < 4; ++j) acc[i][j] = 0.0f;

    #pragma unroll 1
    for (int dc = 0; dc < 256; dc += 16) {
        const float4 xv = *(const float4*)&x[(size_t)(nBase + sr) * 256 + dc + sd];
        const float4 pv = *(const float4*)&pos[(size_t)(n0 + sr) * 256 + dc + sd];
        const float4 wv = *(const float4*)&W[(size_t)(e0 + sr) * 256 + dc + sd];
        __syncthreads();   // previous compute done reading LDS
        Hs[sd + 0][sr] = xv.x + pv.x;
        Hs[sd + 1][sr] = xv.y + pv.y;
        Hs[sd + 2][sr] = xv.z + pv.z;
        Hs[sd + 3][sr] = xv.w + pv.w;
        Ws[sd + 0][sr] = wv.x;
        Ws[sd + 1][sr] = wv.y;
        Ws[sd + 2][sr] = wv.z;
        Ws[sd + 3][sr] = wv.w;
        __syncthreads();
        #pragma unroll
        for (int d = 0; d < 16; ++d) {
            const float4 ev = *(const float4*)&Ws[d][ty << 2];   // e-dim (rows)
            const float4 nv = *(const float4*)&Hs[d][tx << 2];   // n-dim (cols)
            const float a4[4] = {ev.x, ev.y, ev.z, ev.w};
            const float b4[4] = {nv.x, nv.y, nv.z, nv.w};
            #pragma unroll
            for (int i = 0; i < 4; ++i)
                #pragma unroll
                for (int j = 0; j < 4; ++j)
                    acc[i][j] = fmaf(a4[i], b4[j], acc[i][j]);
        }
    }

    const float4 bv4 = *(const float4*)&bias[e0 + (ty << 2)];
    const float bb[4] = {bv4.x, bv4.y, bv4.z, bv4.w};
    #pragma unroll
    for (int i = 0; i < 4; ++i)
        #pragma unroll
        for (int j = 0; j < 4; ++j) acc[i][j] += bb[i];

    // coalesced transposed stores: row e = e0+4ty+i, cols n0+4tx..+3
    #pragma unroll
    for (int i = 0; i < 4; ++i) {
        float4 o;
        o.x = acc[i][0]; o.y = acc[i][1]; o.z = acc[i][2]; o.w = acc[i][3];
        *(float4*)&Og[(size_t)((b << 8) + e0 + (ty << 2) + i) * 1024 + n0 + (tx << 2)] = o;
    }
}

// ---------------------------------------------------------------------------
// Kernel B v9: scores + softmax + top-16, fused.
// One WG = (batch b, 16 rows), 256 threads = 4 waves; wave w owns cols
// [256w, 256w+256), lane owns 4 adjacent cols -> acc[16][4] = 64 VGPRs.
// v9 changes vs v8 (memory now clean; ~50% latency stall remains):
//  - d+=4 main loop: next 4 K d-steps issued ~512 issue-cycles ahead of
//    use -> covers L2 latency with margin; 64 iterations.
//  - Epilogue: 2 passes x 8 rows (Sc[8][1024], 32 KB); each wave extracts
//    TWO rows concurrently (paired rounds) so the serial scan + 6-step
//    64-bit reduce chains of the two rows overlap. All acc indices remain
//    compile-time (pass loop fully unrolled) -> no scratch.
// ---------------------------------------------------------------------------
__global__ __launch_bounds__(256, 4) void adj_topk_kernel(
    const float* __restrict__ Qt, const float* __restrict__ Kt,
    float* __restrict__ out)
{
    __shared__ __align__(16) float SB[8192];      // 32 KB, dual-purpose
    float (*Qlds)[16]  = (float(*)[16])SB;        // [256][16] main loop
    float (*Sc)[1024]  = (float(*)[1024])SB;      // [8][1024]  epilogue

    const int tid  = threadIdx.x;
    const int lane = tid & 63;
    const int w    = tid >> 6;                    // 0..3
    const int bid  = ((blockIdx.x & 7) << 8) + (blockIdx.x >> 3);  // XCD swizzle
    const int b       = bid >> 6;
    const int rowBase = (bid & 63) << 4;

    const float* __restrict__ Qb = Qt + (size_t)b * (256 * 1024) + rowBase;
    const float* __restrict__ kp = Kt + (size_t)b * (256 * 1024) + (w << 8) + (lane << 2);

    // ---- stage Q tile into LDS: Qlds[d][r] = Qb[d*1024 + r], r<16 ----
    {
        const int d0 = tid >> 2;              // 0..63
        const int rc = (tid & 3) << 2;        // 0,4,8,12
        #pragma unroll
        for (int p = 0; p < 4; ++p) {
            const int d = d0 + (p << 6);
            *(float4*)&Qlds[d][rc] = *(const float4*)&Qb[(size_t)d * 1024 + rc];
        }
    }
    __syncthreads();

    float acc[16][4];
    #pragma unroll
    for (int r = 0; r < 16; ++r)
        #pragma unroll
        for (int c = 0; c < 4; ++c) acc[r][c] = 0.0f;

    // ---- prefetch K for d=0..3 ----
    float4 kc[4];
    #pragma unroll
    for (int q = 0; q < 4; ++q)
        kc[q] = *(const float4*)&kp[(size_t)q * 1024];

    // ---- main loop: 64 chunks of 4 d-steps, barrier-free ----
    #pragma unroll 1
    for (int d = 0; d < 256; d += 4) {
        const int dn = (d + 4) & 255;          // wrap: final prefetch harmless
        float4 kn[4];
        #pragma unroll
        for (int q = 0; q < 4; ++q)
            kn[q] = *(const float4*)&kp[(size_t)(dn + q) * 1024];

        #pragma unroll
        for (int dd = 0; dd < 4; ++dd) {
            #pragma unroll
            for (int g = 0; g < 4; ++g) {
                const float4 qv = *(const float4*)&Qlds[d + dd][g << 2]; // bcast
                const float qa[4] = {qv.x, qv.y, qv.z, qv.w};
                #pragma unroll
                for (int j = 0; j < 4; ++j) {
                    const int r = (g << 2) + j;
                    acc[r][0] = fmaf(qa[j], kc[dd].x, acc[r][0]);
                    acc[r][1] = fmaf(qa[j], kc[dd].y, acc[r][1]);
                    acc[r][2] = fmaf(qa[j], kc[dd].z, acc[r][2]);
                    acc[r][3] = fmaf(qa[j], kc[dd].w, acc[r][3]);
                }
            }
        }
        #pragma unroll
        for (int q = 0; q < 4; ++q) kc[q] = kn[q];
    }

    // ---- epilogue: 2 passes of 8 rows; 2 rows per wave, interleaved ----
    const int growBase = b * 1024 + rowBase;

    #pragma unroll
    for (int p = 0; p < 2; ++p) {     // FULL unroll: p compile-time
        __syncthreads();              // Qlds / prior pass reads complete
        #pragma unroll
        for (int rr = 0; rr < 8; ++rr) {
            float4 v;
            v.x = acc[(p << 3) + rr][0];
            v.y = acc[(p << 3) + rr][1];
            v.z = acc[(p << 3) + rr][2];
            v.w = acc[(p << 3) + rr][3];
            *(float4*)&Sc[rr][(w << 8) + (lane << 2)] = v;
        }
        __syncthreads();

        // wave w owns rows 2w, 2w+1 of this pass; process both concurrently
        float s0[16], s1[16];
        #pragma unroll
        for (int o = 0; o < 4; ++o) {
            const float4 a = *(const float4*)&Sc[(w << 1) + 0][(o << 8) + (lane << 2)];
            const float4 c = *(const float4*)&Sc[(w << 1) + 1][(o << 8) + (lane << 2)];
            s0[(o << 2) + 0] = a.x * 0.0625f;
            s0[(o << 2) + 1] = a.y * 0.0625f;
            s0[(o << 2) + 2] = a.z * 0.0625f;
            s0[(o << 2) + 3] = a.w * 0.0625f;
            s1[(o << 2) + 0] = c.x * 0.0625f;
            s1[(o << 2) + 1] = c.y * 0.0625f;
            s1[(o << 2) + 2] = c.z * 0.0625f;
            s1[(o << 2) + 3] = c.w * 0.0625f;
        }

        // row max (wave butterfly), both rows interleaved
        float mx0 = s0[0], mx1 = s1[0];
        #pragma unroll
        for (int i = 1; i < 16; ++i) {
            mx0 = fmaxf(mx0, s0[i]);
            mx1 = fmaxf(mx1, s1[i]);
        }
        #pragma unroll
        for (int off = 32; off > 0; off >>= 1) {
            mx0 = fmaxf(mx0, __shfl_xor(mx0, off));
            mx1 = fmaxf(mx1, __shfl_xor(mx1, off));
        }

        // softmax denominator, both rows interleaved
        float ls0 = 0.f, ls1 = 0.f;
        #pragma unroll
        for (int i = 0; i < 16; ++i) {
            ls0 += __expf(s0[i] - mx0);
            ls1 += __expf(s1[i] - mx1);
        }
        #pragma unroll
        for (int off = 32; off > 0; off >>= 1) {
            ls0 += __shfl_xor(ls0, off);
            ls1 += __shfl_xor(ls1, off);
        }
        const float rZ0 = 1.0f / ls0;
        const float rZ1 = 1.0f / ls1;

        // top-16 extraction on destructible copies (s0/s1 ARE the copies;
        // final write re-reads Sc); winners -> bitmasks
        unsigned mask0 = 0u, mask1 = 0u;
        #pragma unroll 1
        for (int j = 0; j < KNNK; ++j) {
            float bv0 = s0[0], bv1 = s1[0];
            int   bi0 = 0,     bi1 = 0;
            #pragma unroll
            for (int i = 1; i < 16; ++i) {
                const bool c0 = s0[i] > bv0;   // strict >, ascending slot scan
                bv0 = c0 ? s0[i] : bv0;
                bi0 = c0 ? i     : bi0;
                const bool c1 = s1[i] > bv1;
                bv1 = c1 ? s1[i] : bv1;
                bi1 = c1 ? i     : bi1;
            }
            const int bm0 = ((bi0 >> 2) << 8) + (lane << 2) + (bi0 & 3);
            const int bm1 = ((bi1 >> 2) << 8) + (lane << 2) + (bi1 & 3);
            const unsigned ub0   = __float_as_uint(bv0);
            const unsigned ub1   = __float_as_uint(bv1);
            const unsigned mono0 = ub0 ^ (unsigned)(((int)ub0 >> 31) | 0x80000000);
            const unsigned mono1 = ub1 ^ (unsigned)(((int)ub1 >> 31) | 0x80000000);
            const unsigned long long key0 =
                ((unsigned long long)mono0 << 32) | (unsigned)(~bm0);
            const unsigned long long key1 =
                ((unsigned long long)mono1 << 32) | (unsigned)(~bm1);
            unsigned long long gk0 = key0, gk1 = key1;
            #pragma unroll
            for (int off = 32; off > 0; off >>= 1) {
                const unsigned long long o0 = __shfl_xor(gk0, off);
                const unsigned long long o1 = __shfl_xor(gk1, off);
                gk0 = (o0 > gk0) ? o0 : gk0;
                gk1 = (o1 > gk1) ? o1 : gk1;
            }
            if (key0 == gk0) {               // unique winner lane, row 0
                mask0 |= (1u << bi0);
                #pragma unroll
                for (int i = 0; i < 16; ++i)
                    s0[i] = (i == bi0) ? -__builtin_inff() : s0[i];
            }
            if (key1 == gk1) {               // unique winner lane, row 1
                mask1 |= (1u << bi1);
                #pragma unroll
                for (int i = 0; i < 16; ++i)
                    s1[i] = (i == bi1) ? -__builtin_inff() : s1[i];
            }
        }

        // full-coverage coalesced writes; values re-read from Sc (bit-identical)
        {
            float* orow = out + ((size_t)(growBase + (p << 3) + (w << 1) + 0)) * 1024;
            #pragma unroll
            for (int o = 0; o < 4; ++o) {
                const float4 sv = *(const float4*)&Sc[(w << 1) + 0][(o << 8) + (lane << 2)];
                float4 v;
                v.x = ((mask0 >> ((o << 2) + 0)) & 1u) ? __expf(sv.x * 0.0625f - mx0) * rZ0 : 0.f;
                v.y = ((mask0 >> ((o << 2) + 1)) & 1u) ? __expf(sv.y * 0.0625f - mx0) * rZ0 : 0.f;
                v.z = ((mask0 >> ((o << 2) + 2)) & 1u) ? __expf(sv.z * 0.0625f - mx0) * rZ0 : 0.f;
                v.w = ((mask0 >> ((o << 2) + 3)) & 1u) ? __expf(sv.w * 0.0625f - mx0) * rZ0 : 0.f;
                *(float4*)&orow[(lane << 2) + (o << 8)] = v;
            }
        }
        {
            float* orow = out + ((size_t)(growBase + (p << 3) + (w << 1) + 1)) * 1024;
            #pragma unroll
            for (int o = 0; o < 4; ++o) {
                const float4 sv = *(const float4*)&Sc[(w << 1) + 1][(o << 8) + (lane << 2)];
                float4 v;
                v.x = ((mask1 >> ((o << 2) + 0)) & 1u) ? __expf(sv.x * 0.0625f - mx1) * rZ1 : 0.f;
                v.y = ((mask1 >> ((o << 2) + 1)) & 1u) ? __expf(sv.y * 0.0625f - mx1) * rZ1 : 0.f;
                v.z = ((mask1 >> ((o << 2) + 2)) & 1u) ? __expf(sv.z * 0.0625f - mx1) * rZ1 : 0.f;
                v.w = ((mask1 >> ((o << 2) + 3)) & 1u) ? __expf(sv.w * 0.0625f - mx1) * rZ1 : 0.f;
                *(float4*)&orow[(lane << 2) + (o << 8)] = v;
            }
        }
    }
}

extern "C" void kernel_launch(void* const* d_in, const int* in_sizes, int n_in,
                              void* d_out, int out_size, void* d_ws, size_t ws_size,
                              hipStream_t stream)
{
    const float* x   = (const float*)d_in[0];
    const float* pos = (const float*)d_in[1];
    const float* wq  = (const float*)d_in[2];
    const float* bq  = (const float*)d_in[3];
    const float* wk  = (const float*)d_in[4];
    const float* bk  = (const float*)d_in[5];
    float* out = (float*)d_out;

    float* Qt = (float*)d_ws;                    // 32 MB: [B, 256, 1024]
    float* Kt = Qt + (size_t)NB * NN * ND;       // 32 MB: [B, 256, 1024]

    proj_kernel<<<dim3(4096), dim3(256), 0, stream>>>(x, pos, wq, bq, wk, bk, Qt, Kt);
    adj_topk_kernel<<<dim3(2048), dim3(256), 0, stream>>>(Qt, Kt, out);
}

// Round 11
// 433.993 us; speedup vs baseline: 1.0629x; 1.0629x over previous
//
#include <hip/hip_runtime.h>
#include <cstdint>
#include <cstddef>

#define NB 32
#define NN 1024
#define ND 256
#define KNNK 16

typedef float f32x2 __attribute__((ext_vector_type(2)));

// ---------------------------------------------------------------------------
// Kernel A v3: fused positional-add + dual projection GEMM, TRANSPOSED out:
//   Qt [B, 256, 1024], Kt [B, 256, 1024]   (out[e][n] = sum_d h[n][d] w[e][d])
// Tile: 64 e x 64 n, 256 threads, 4x4 microtile. (measured ~90-110 us)
// ---------------------------------------------------------------------------
__global__ __launch_bounds__(256) void proj_kernel(
    const float* __restrict__ x, const float* __restrict__ pos,
    const float* __restrict__ wq, const float* __restrict__ bq,
    const float* __restrict__ wk, const float* __restrict__ bk,
    float* __restrict__ Qt, float* __restrict__ Kt)
{
    __shared__ __align__(16) float Hs[16][64];   // [d][n_local]
    __shared__ __align__(16) float Ws[16][64];   // [d][e_local]

    const int tid = threadIdx.x;
    const int tx = tid & 15;          // n microtile index
    const int ty = tid >> 4;          // e microtile index
    const int bm = blockIdx.x >> 3;   // 0..511 n tiles (b*16 + ntile)
    const int be = blockIdx.x & 7;    // 0..7 e tiles (0-3 -> Q, 4-7 -> K)
    const int nBase = bm << 6;        // global flattened n base (b*1024 + n0)
    const int b  = nBase >> 10;
    const int n0 = nBase & 1023;
    const int eBase = be << 6;
    const bool isQ = (eBase < 256);
    const float* __restrict__ W    = isQ ? wq : wk;
    const float* __restrict__ bias = isQ ? bq : bk;
    float* __restrict__ Og         = isQ ? Qt : Kt;
    const int e0 = isQ ? eBase : (eBase - 256);

    const int sr = tid >> 2;          // 0..63 (n or e index for staging)
    const int sd = (tid & 3) << 2;    // 0,4,8,12

    float acc[4][4];
    #pragma unroll
    for (int i = 0; i < 4; ++i)
        #pragma unroll
        for (int j = 0; j < 4; ++j) acc[i][j] = 0.0f;

    #pragma unroll 1
    for (int dc = 0; dc < 256; dc += 16) {
        const float4 xv = *(const float4*)&x[(size_t)(nBase + sr) * 256 + dc + sd];
        const float4 pv = *(const float4*)&pos[(size_t)(n0 + sr) * 256 + dc + sd];
        const float4 wv = *(const float4*)&W[(size_t)(e0 + sr) * 256 + dc + sd];
        __syncthreads();   // previous compute done reading LDS
        Hs[sd + 0][sr] = xv.x + pv.x;
        Hs[sd + 1][sr] = xv.y + pv.y;
        Hs[sd + 2][sr] = xv.z + pv.z;
        Hs[sd + 3][sr] = xv.w + pv.w;
        Ws[sd + 0][sr] = wv.x;
        Ws[sd + 1][sr] = wv.y;
        Ws[sd + 2][sr] = wv.z;
        Ws[sd + 3][sr] = wv.w;
        __syncthreads();
        #pragma unroll
        for (int d = 0; d < 16; ++d) {
            const float4 ev = *(const float4*)&Ws[d][ty << 2];   // e-dim (rows)
            const float4 nv = *(const float4*)&Hs[d][tx << 2];   // n-dim (cols)
            const float a4[4] = {ev.x, ev.y, ev.z, ev.w};
            const float b4[4] = {nv.x, nv.y, nv.z, nv.w};
            #pragma unroll
            for (int i = 0; i < 4; ++i)
                #pragma unroll
                for (int j = 0; j < 4; ++j)
                    acc[i][j] = fmaf(a4[i], b4[j], acc[i][j]);
        }
    }

    const float4 bv4 = *(const float4*)&bias[e0 + (ty << 2)];
    const float bb[4] = {bv4.x, bv4.y, bv4.z, bv4.w};
    #pragma unroll
    for (int i = 0; i < 4; ++i)
        #pragma unroll
        for (int j = 0; j < 4; ++j) acc[i][j] += bb[i];

    // coalesced transposed stores: row e = e0+4ty+i, cols n0+4tx..+3
    #pragma unroll
    for (int i = 0; i < 4; ++i) {
        float4 o;
        o.x = acc[i][0]; o.y = acc[i][1]; o.z = acc[i][2]; o.w = acc[i][3];
        *(float4*)&Og[(size_t)((b << 8) + e0 + (ty << 2) + i) * 1024 + n0 + (tx << 2)] = o;
    }
}

// ---------------------------------------------------------------------------
// Kernel B v11: scores + softmax + top-16, fused.
// One WG = (batch b, 16 rows), 256 threads = 4 waves; wave w owns cols
// [256w, 256w+256), lane owns 4 adjacent cols.
// v11 = v10 with FIXED v_pk_fma_f32 asm: VOP3P needs 64-bit PAIR operands;
// Q is passed as the adjacent pair {q0,q1}/{q2,q3} and op_sel/op_sel_hi on
// src0 broadcasts the chosen half to both packed lanes:
//   lo-broadcast: op_sel:[0,0,0] op_sel_hi:[0,1,1]
//   hi-broadcast: op_sel:[1,0,0] op_sel_hi:[1,1,1]
// Each half is a bit-identical IEEE fp32 FMA in the same accumulation order
// -> absmax must stay exactly 1.220703e-4. Tests CDNA4 packed-fp32 rate
// (main-loop instr count 16384 -> 8192 per wave).
// ---------------------------------------------------------------------------
__global__ __launch_bounds__(256, 4) void adj_topk_kernel(
    const float* __restrict__ Qt, const float* __restrict__ Kt,
    float* __restrict__ out)
{
    __shared__ __align__(16) float SB[8192];      // 32 KB, dual-purpose
    float (*Qlds)[16]  = (float(*)[16])SB;        // [256][16] main loop
    float (*Sc)[1024]  = (float(*)[1024])SB;      // [8][1024]  epilogue

    const int tid  = threadIdx.x;
    const int lane = tid & 63;
    const int w    = tid >> 6;                    // 0..3
    const int bid  = ((blockIdx.x & 7) << 8) + (blockIdx.x >> 3);  // XCD swizzle
    const int b       = bid >> 6;
    const int rowBase = (bid & 63) << 4;

    const float* __restrict__ Qb = Qt + (size_t)b * (256 * 1024) + rowBase;
    const float* __restrict__ kp = Kt + (size_t)b * (256 * 1024) + (w << 8) + (lane << 2);

    // ---- stage Q tile into LDS: Qlds[d][r] = Qb[d*1024 + r], r<16 ----
    {
        const int d0 = tid >> 2;              // 0..63
        const int rc = (tid & 3) << 2;        // 0,4,8,12
        #pragma unroll
        for (int p = 0; p < 4; ++p) {
            const int d = d0 + (p << 6);
            *(float4*)&Qlds[d][rc] = *(const float4*)&Qb[(size_t)d * 1024 + rc];
        }
    }
    __syncthreads();

    f32x2 acc[16][2];                         // [row][col pair]
    #pragma unroll
    for (int r = 0; r < 16; ++r) {
        acc[r][0] = (f32x2){0.f, 0.f};
        acc[r][1] = (f32x2){0.f, 0.f};
    }

    // ---- prefetch K for d=0..3 ----
    float4 kc[4];
    #pragma unroll
    for (int q = 0; q < 4; ++q)
        kc[q] = *(const float4*)&kp[(size_t)q * 1024];

    // ---- main loop: 64 chunks of 4 d-steps, barrier-free ----
    #pragma unroll 1
    for (int d = 0; d < 256; d += 4) {
        const int dn = (d + 4) & 255;          // wrap: final prefetch harmless
        float4 kn[4];
        #pragma unroll
        for (int q = 0; q < 4; ++q)
            kn[q] = *(const float4*)&kp[(size_t)(dn + q) * 1024];

        #pragma unroll
        for (int dd = 0; dd < 4; ++dd) {
            f32x2 kA, kB;
            kA.x = kc[dd].x; kA.y = kc[dd].y;
            kB.x = kc[dd].z; kB.y = kc[dd].w;
            #pragma unroll
            for (int g = 0; g < 4; ++g) {
                const f32x2 qlo = *(const f32x2*)&Qlds[d + dd][(g << 2) + 0]; // {q0,q1}
                const f32x2 qhi = *(const f32x2*)&Qlds[d + dd][(g << 2) + 2]; // {q2,q3}
                const int r = g << 2;
                // row r+0: q = qlo.lo broadcast
                asm("v_pk_fma_f32 %0, %1, %2, %0 op_sel:[0,0,0] op_sel_hi:[0,1,1]"
                    : "+v"(acc[r + 0][0]) : "v"(qlo), "v"(kA));
                asm("v_pk_fma_f32 %0, %1, %2, %0 op_sel:[0,0,0] op_sel_hi:[0,1,1]"
                    : "+v"(acc[r + 0][1]) : "v"(qlo), "v"(kB));
                // row r+1: q = qlo.hi broadcast
                asm("v_pk_fma_f32 %0, %1, %2, %0 op_sel:[1,0,0] op_sel_hi:[1,1,1]"
                    : "+v"(acc[r + 1][0]) : "v"(qlo), "v"(kA));
                asm("v_pk_fma_f32 %0, %1, %2, %0 op_sel:[1,0,0] op_sel_hi:[1,1,1]"
                    : "+v"(acc[r + 1][1]) : "v"(qlo), "v"(kB));
                // row r+2: q = qhi.lo broadcast
                asm("v_pk_fma_f32 %0, %1, %2, %0 op_sel:[0,0,0] op_sel_hi:[0,1,1]"
                    : "+v"(acc[r + 2][0]) : "v"(qhi), "v"(kA));
                asm("v_pk_fma_f32 %0, %1, %2, %0 op_sel:[0,0,0] op_sel_hi:[0,1,1]"
                    : "+v"(acc[r + 2][1]) : "v"(qhi), "v"(kB));
                // row r+3: q = qhi.hi broadcast
                asm("v_pk_fma_f32 %0, %1, %2, %0 op_sel:[1,0,0] op_sel_hi:[1,1,1]"
                    : "+v"(acc[r + 3][0]) : "v"(qhi), "v"(kA));
                asm("v_pk_fma_f32 %0, %1, %2, %0 op_sel:[1,0,0] op_sel_hi:[1,1,1]"
                    : "+v"(acc[r + 3][1]) : "v"(qhi), "v"(kB));
            }
        }
        #pragma unroll
        for (int q = 0; q < 4; ++q) kc[q] = kn[q];
    }

    // ---- epilogue: 2 passes of 8 rows; 2 rows per wave, interleaved ----
    const int growBase = b * 1024 + rowBase;

    #pragma unroll
    for (int p = 0; p < 2; ++p) {     // FULL unroll: p compile-time
        __syncthreads();              // Qlds / prior pass reads complete
        #pragma unroll
        for (int rr = 0; rr < 8; ++rr) {
            float4 v;
            v.x = acc[(p << 3) + rr][0].x;
            v.y = acc[(p << 3) + rr][0].y;
            v.z = acc[(p << 3) + rr][1].x;
            v.w = acc[(p << 3) + rr][1].y;
            *(float4*)&Sc[rr][(w << 8) + (lane << 2)] = v;
        }
        __syncthreads();

        // wave w owns rows 2w, 2w+1 of this pass; process both concurrently
        float s0[16], s1[16];
        #pragma unroll
        for (int o = 0; o < 4; ++o) {
            const float4 a = *(const float4*)&Sc[(w << 1) + 0][(o << 8) + (lane << 2)];
            const float4 c = *(const float4*)&Sc[(w << 1) + 1][(o << 8) + (lane << 2)];
            s0[(o << 2) + 0] = a.x * 0.0625f;
            s0[(o << 2) + 1] = a.y * 0.0625f;
            s0[(o << 2) + 2] = a.z * 0.0625f;
            s0[(o << 2) + 3] = a.w * 0.0625f;
            s1[(o << 2) + 0] = c.x * 0.0625f;
            s1[(o << 2) + 1] = c.y * 0.0625f;
            s1[(o << 2) + 2] = c.z * 0.0625f;
            s1[(o << 2) + 3] = c.w * 0.0625f;
        }

        // row max (wave butterfly), both rows interleaved
        float mx0 = s0[0], mx1 = s1[0];
        #pragma unroll
        for (int i = 1; i < 16; ++i) {
            mx0 = fmaxf(mx0, s0[i]);
            mx1 = fmaxf(mx1, s1[i]);
        }
        #pragma unroll
        for (int off = 32; off > 0; off >>= 1) {
            mx0 = fmaxf(mx0, __shfl_xor(mx0, off));
            mx1 = fmaxf(mx1, __shfl_xor(mx1, off));
        }

        // softmax denominator, both rows interleaved
        float ls0 = 0.f, ls1 = 0.f;
        #pragma unroll
        for (int i = 0; i < 16; ++i) {
            ls0 += __expf(s0[i] - mx0);
            ls1 += __expf(s1[i] - mx1);
        }
        #pragma unroll
        for (int off = 32; off > 0; off >>= 1) {
            ls0 += __shfl_xor(ls0, off);
            ls1 += __shfl_xor(ls1, off);
        }
        const float rZ0 = 1.0f / ls0;
        const float rZ1 = 1.0f / ls1;

        // top-16 extraction on destructible copies (s0/s1 ARE the copies;
        // final write re-reads Sc); winners -> bitmasks
        unsigned mask0 = 0u, mask1 = 0u;
        #pragma unroll 1
        for (int j = 0; j < KNNK; ++j) {
            float bv0 = s0[0], bv1 = s1[0];
            int   bi0 = 0,     bi1 = 0;
            #pragma unroll
            for (int i = 1; i < 16; ++i) {
                const bool c0 = s0[i] > bv0;   // strict >, ascending slot scan
                bv0 = c0 ? s0[i] : bv0;
                bi0 = c0 ? i     : bi0;
                const bool c1 = s1[i] > bv1;
                bv1 = c1 ? s1[i] : bv1;
                bi1 = c1 ? i     : bi1;
            }
            const int bm0 = ((bi0 >> 2) << 8) + (lane << 2) + (bi0 & 3);
            const int bm1 = ((bi1 >> 2) << 8) + (lane << 2) + (bi1 & 3);
            const unsigned ub0   = __float_as_uint(bv0);
            const unsigned ub1   = __float_as_uint(bv1);
            const unsigned mono0 = ub0 ^ (unsigned)(((int)ub0 >> 31) | 0x80000000);
            const unsigned mono1 = ub1 ^ (unsigned)(((int)ub1 >> 31) | 0x80000000);
            const unsigned long long key0 =
                ((unsigned long long)mono0 << 32) | (unsigned)(~bm0);
            const unsigned long long key1 =
                ((unsigned long long)mono1 << 32) | (unsigned)(~bm1);
            unsigned long long gk0 = key0, gk1 = key1;
            #pragma unroll
            for (int off = 32; off > 0; off >>= 1) {
                const unsigned long long o0 = __shfl_xor(gk0, off);
                const unsigned long long o1 = __shfl_xor(gk1, off);
                gk0 = (o0 > gk0) ? o0 : gk0;
                gk1 = (o1 > gk1) ? o1 : gk1;
            }
            if (key0 == gk0) {               // unique winner lane, row 0
                mask0 |= (1u << bi0);
                #pragma unroll
                for (int i = 0; i < 16; ++i)
                    s0[i] = (i == bi0) ? -__builtin_inff() : s0[i];
            }
            if (key1 == gk1) {               // unique winner lane, row 1
                mask1 |= (1u << bi1);
                #pragma unroll
                for (int i = 0; i < 16; ++i)
                    s1[i] = (i == bi1) ? -__builtin_inff() : s1[i];
            }
        }

        // full-coverage coalesced writes; values re-read from Sc (bit-identical)
        {
            float* orow = out + ((size_t)(growBase + (p << 3) + (w << 1) + 0)) * 1024;
            #pragma unroll
            for (int o = 0; o < 4; ++o) {
                const float4 sv = *(const float4*)&Sc[(w << 1) + 0][(o << 8) + (lane << 2)];
                float4 v;
                v.x = ((mask0 >> ((o << 2) + 0)) & 1u) ? __expf(sv.x * 0.0625f - mx0) * rZ0 : 0.f;
                v.y = ((mask0 >> ((o << 2) + 1)) & 1u) ? __expf(sv.y * 0.0625f - mx0) * rZ0 : 0.f;
                v.z = ((mask0 >> ((o << 2) + 2)) & 1u) ? __expf(sv.z * 0.0625f - mx0) * rZ0 : 0.f;
                v.w = ((mask0 >> ((o << 2) + 3)) & 1u) ? __expf(sv.w * 0.0625f - mx0) * rZ0 : 0.f;
                *(float4*)&orow[(lane << 2) + (o << 8)] = v;
            }
        }
        {
            float* orow = out + ((size_t)(growBase + (p << 3) + (w << 1) + 1)) * 1024;
            #pragma unroll
            for (int o = 0; o < 4; ++o) {
                const float4 sv = *(const float4*)&Sc[(w << 1) + 1][(o << 8) + (lane << 2)];
                float4 v;
                v.x = ((mask1 >> ((o << 2) + 0)) & 1u) ? __expf(sv.x * 0.0625f - mx1) * rZ1 : 0.f;
                v.y = ((mask1 >> ((o << 2) + 1)) & 1u) ? __expf(sv.y * 0.0625f - mx1) * rZ1 : 0.f;
                v.z = ((mask1 >> ((o << 2) + 2)) & 1u) ? __expf(sv.z * 0.0625f - mx1) * rZ1 : 0.f;
                v.w = ((mask1 >> ((o << 2) + 3)) & 1u) ? __expf(sv.w * 0.0625f - mx1) * rZ1 : 0.f;
                *(float4*)&orow[(lane << 2) + (o << 8)] = v;
            }
        }
    }
}

extern "C" void kernel_launch(void* const* d_in, const int* in_sizes, int n_in,
                              void* d_out, int out_size, void* d_ws, size_t ws_size,
                              hipStream_t stream)
{
    const float* x   = (const float*)d_in[0];
    const float* pos = (const float*)d_in[1];
    const float* wq  = (const float*)d_in[2];
    const float* bq  = (const float*)d_in[3];
    const float* wk  = (const float*)d_in[4];
    const float* bk  = (const float*)d_in[5];
    float* out = (float*)d_out;

    float* Qt = (float*)d_ws;                    // 32 MB: [B, 256, 1024]
    float* Kt = Qt + (size_t)NB * NN * ND;       // 32 MB: [B, 256, 1024]

    proj_kernel<<<dim3(4096), dim3(256), 0, stream>>>(x, pos, wq, bq, wk, bk, Qt, Kt);
    adj_topk_kernel<<<dim3(2048), dim3(256), 0, stream>>>(Qt, Kt, out);
}